// Round 2
// baseline (468.845 us; speedup 1.0000x reference)
//
#include <hip/hip_runtime.h>

// Problem constants (match reference)
#define NN    100000
#define EE    1000000
#define DD    32
#define HID   64
#define RELF  128          // 4*D
#define EPSF  1e-8f

// One thread per edge. rel[128] held fully in VGPRs (launch_bounds(256,1)
// lifts the register cap -> no scratch spill). Weights are read through the
// scalar pipe: W1 addresses are wave-uniform, so the compiler emits
// s_load_dwordx16 and v_fmac_f32 consumes the SGPR operand directly.
// No LDS at all -> no ds_read issue cost, no LDS occupancy cap.
__global__ __launch_bounds__(256, 1)
void edge_bias_kernel(const float* __restrict__ x,
                      const int*   __restrict__ edge_index,   // [2, E] flattened
                      const float* __restrict__ W1,           // [HID, RELF]
                      const float* __restrict__ b1,           // [HID]
                      const float* __restrict__ W2,           // [1, HID]
                      const float* __restrict__ b2,           // [1]
                      float*       __restrict__ out,          // [E]
                      int E)
{
    int e = blockIdx.x * blockDim.x + threadIdx.x;
    if (e >= E) return;

    int src = edge_index[e];        // row 0: source indices
    int dst = edge_index[E + e];    // row 1: target indices

    const float4* xi4 = (const float4*)(x + (long)src * DD);
    const float4* xj4 = (const float4*)(x + (long)dst * DD);

    // Relation features in registers: [ratio | log_ratio | abs_diff | rel_diff]
    float rel[RELF];
    #pragma unroll
    for (int q = 0; q < DD / 4; ++q) {
        float4 a = xi4[q];
        float4 b = xj4[q];
        float ai[4] = {a.x, a.y, a.z, a.w};
        float bj[4] = {b.x, b.y, b.z, b.w};
        #pragma unroll
        for (int t = 0; t < 4; ++t) {
            int d = q * 4 + t;
            float xi = ai[t];
            float xj = bj[t];
            float ratio = xi * __builtin_amdgcn_rcpf(xj + EPSF);
            float logr  = __logf(xi + EPSF) - __logf(xj + EPSF);
            float ad    = fabsf(xi - xj);
            float rd    = ad * __builtin_amdgcn_rcpf(fmaxf(xi, xj) + EPSF);
            rel[0 * DD + d] = ratio;
            rel[1 * DD + d] = logr;
            rel[2 * DD + d] = ad;
            rel[3 * DD + d] = rd;
        }
    }

    // MLP: out = b2 + sum_h relu(b1[h] + rel . W1[h,:]) * W2[h]
    // h-loop kept dynamic (64 iters); weights flow through the scalar cache.
    float result = b2[0];
    #pragma unroll 2
    for (int h = 0; h < HID; ++h) {
        const float* __restrict__ w = W1 + h * RELF;   // wave-uniform address
        float a0 = 0.f, a1 = 0.f, a2 = 0.f, a3 = 0.f;
        #pragma unroll
        for (int k = 0; k < RELF; k += 4) {
            a0 = fmaf(rel[k + 0], w[k + 0], a0);
            a1 = fmaf(rel[k + 1], w[k + 1], a1);
            a2 = fmaf(rel[k + 2], w[k + 2], a2);
            a3 = fmaf(rel[k + 3], w[k + 3], a3);
        }
        float acc = ((a0 + a1) + (a2 + a3)) + b1[h];
        result = fmaf(fmaxf(acc, 0.f), W2[h], result);
    }
    out[e] = result;
}

extern "C" void kernel_launch(void* const* d_in, const int* in_sizes, int n_in,
                              void* d_out, int out_size, void* d_ws, size_t ws_size,
                              hipStream_t stream)
{
    const float* x   = (const float*)d_in[0];
    const int*   ei  = (const int*)  d_in[1];
    const float* W1  = (const float*)d_in[2];
    const float* b1  = (const float*)d_in[3];
    const float* W2  = (const float*)d_in[4];
    const float* b2  = (const float*)d_in[5];
    float* out = (float*)d_out;

    int E = out_size;  // 1,000,000
    int block = 256;
    int grid = (E + block - 1) / block;
    edge_bias_kernel<<<grid, block, 0, stream>>>(x, ei, W1, b1, W2, b2, out, E);
}

// Round 3
// 461.950 us; speedup vs baseline: 1.0149x; 1.0149x over previous
//
#include <hip/hip_runtime.h>

// Problem constants (match reference)
#define NN    100000
#define EE    1000000
#define DD    32
#define HID   64
#define RELF  128          // 4*D
#define EPSF  1e-8f

// One thread per edge. The 128 relation features are held in 128 NAMED scalar
// variables (X-macro generated) -- no alloca, so SROA/PromoteAlloca cannot
// park them in scratch (round-1/2 failure mode: VGPR_Count=76..88 with the
// float rel[128] array spilled from the start).
// Weights stream through the scalar path: W1 + h*128 is wave-uniform ->
// s_load_dwordx16, and v_fmac_f32 takes the SGPR operand directly.

// ---- feature computation: d, xi-component, xj-component ----
#define FEAT(RR, RL, RA, RD, XI, XJ)                                        \
    {                                                                       \
        float xi_ = (XI), xj_ = (XJ);                                       \
        RR = xi_ * __builtin_amdgcn_rcpf(xj_ + EPSF);                       \
        RL = __logf(xi_ + EPSF) - __logf(xj_ + EPSF);                       \
        float ad_ = fabsf(xi_ - xj_);                                       \
        RA = ad_;                                                           \
        RD = ad_ * __builtin_amdgcn_rcpf(fmaxf(xi_, xj_) + EPSF);           \
    }

// ---- one quad of the 128-long dot product, 4 independent chains ----
#define DOT(k0, k1, k2, k3)                                                 \
    s0 = fmaf(r##k0, w[k0], s0);                                            \
    s1 = fmaf(r##k1, w[k1], s1);                                            \
    s2 = fmaf(r##k2, w[k2], s2);                                            \
    s3 = fmaf(r##k3, w[k3], s3);

__global__ __launch_bounds__(256, 2)
void edge_bias_kernel(const float* __restrict__ x,
                      const int*   __restrict__ edge_index,   // [2, E] flattened
                      const float* __restrict__ W1,           // [HID, RELF]
                      const float* __restrict__ b1,           // [HID]
                      const float* __restrict__ W2,           // [1, HID]
                      const float* __restrict__ b2,           // [1]
                      float*       __restrict__ out,          // [E]
                      int E)
{
    int e = blockIdx.x * blockDim.x + threadIdx.x;
    if (e >= E) return;

    int src = edge_index[e];        // row 0: source indices
    int dst = edge_index[E + e];    // row 1: target indices

    const float4* xi4 = (const float4*)(x + (long)src * DD);
    const float4* xj4 = (const float4*)(x + (long)dst * DD);

    float4 a0 = xi4[0], a1 = xi4[1], a2 = xi4[2], a3 = xi4[3];
    float4 a4 = xi4[4], a5 = xi4[5], a6 = xi4[6], a7 = xi4[7];
    float4 b0 = xj4[0], b1v = xj4[1], b2v = xj4[2], b3 = xj4[3];
    float4 b4 = xj4[4], b5 = xj4[5], b6 = xj4[6], b7 = xj4[7];

    // 128 named feature registers: ratio r0-31, log r32-63, abs r64-95, rel r96-127
    float r0,r1,r2,r3,r4,r5,r6,r7,r8,r9,r10,r11,r12,r13,r14,r15;
    float r16,r17,r18,r19,r20,r21,r22,r23,r24,r25,r26,r27,r28,r29,r30,r31;
    float r32,r33,r34,r35,r36,r37,r38,r39,r40,r41,r42,r43,r44,r45,r46,r47;
    float r48,r49,r50,r51,r52,r53,r54,r55,r56,r57,r58,r59,r60,r61,r62,r63;
    float r64,r65,r66,r67,r68,r69,r70,r71,r72,r73,r74,r75,r76,r77,r78,r79;
    float r80,r81,r82,r83,r84,r85,r86,r87,r88,r89,r90,r91,r92,r93,r94,r95;
    float r96,r97,r98,r99,r100,r101,r102,r103,r104,r105,r106,r107;
    float r108,r109,r110,r111,r112,r113,r114,r115,r116,r117,r118,r119;
    float r120,r121,r122,r123,r124,r125,r126,r127;

    FEAT(r0,  r32, r64, r96,  a0.x, b0.x)  FEAT(r1,  r33, r65, r97,  a0.y, b0.y)
    FEAT(r2,  r34, r66, r98,  a0.z, b0.z)  FEAT(r3,  r35, r67, r99,  a0.w, b0.w)
    FEAT(r4,  r36, r68, r100, a1.x, b1v.x) FEAT(r5,  r37, r69, r101, a1.y, b1v.y)
    FEAT(r6,  r38, r70, r102, a1.z, b1v.z) FEAT(r7,  r39, r71, r103, a1.w, b1v.w)
    FEAT(r8,  r40, r72, r104, a2.x, b2v.x) FEAT(r9,  r41, r73, r105, a2.y, b2v.y)
    FEAT(r10, r42, r74, r106, a2.z, b2v.z) FEAT(r11, r43, r75, r107, a2.w, b2v.w)
    FEAT(r12, r44, r76, r108, a3.x, b3.x)  FEAT(r13, r45, r77, r109, a3.y, b3.y)
    FEAT(r14, r46, r78, r110, a3.z, b3.z)  FEAT(r15, r47, r79, r111, a3.w, b3.w)
    FEAT(r16, r48, r80, r112, a4.x, b4.x)  FEAT(r17, r49, r81, r113, a4.y, b4.y)
    FEAT(r18, r50, r82, r114, a4.z, b4.z)  FEAT(r19, r51, r83, r115, a4.w, b4.w)
    FEAT(r20, r52, r84, r116, a5.x, b5.x)  FEAT(r21, r53, r85, r117, a5.y, b5.y)
    FEAT(r22, r54, r86, r118, a5.z, b5.z)  FEAT(r23, r55, r87, r119, a5.w, b5.w)
    FEAT(r24, r56, r88, r120, a6.x, b6.x)  FEAT(r25, r57, r89, r121, a6.y, b6.y)
    FEAT(r26, r58, r90, r122, a6.z, b6.z)  FEAT(r27, r59, r91, r123, a6.w, b6.w)
    FEAT(r28, r60, r92, r124, a7.x, b7.x)  FEAT(r29, r61, r93, r125, a7.y, b7.y)
    FEAT(r30, r62, r94, r126, a7.z, b7.z)  FEAT(r31, r63, r95, r127, a7.w, b7.w)

    // MLP: out = b2 + sum_h relu(b1[h] + rel . W1[h,:]) * W2[h]
    float result = b2[0];
    #pragma unroll 2
    for (int h = 0; h < HID; ++h) {
        const float* __restrict__ w = W1 + h * RELF;   // wave-uniform address
        float s0 = 0.f, s1 = 0.f, s2 = 0.f, s3 = 0.f;
        DOT(0,1,2,3)       DOT(4,5,6,7)       DOT(8,9,10,11)     DOT(12,13,14,15)
        DOT(16,17,18,19)   DOT(20,21,22,23)   DOT(24,25,26,27)   DOT(28,29,30,31)
        DOT(32,33,34,35)   DOT(36,37,38,39)   DOT(40,41,42,43)   DOT(44,45,46,47)
        DOT(48,49,50,51)   DOT(52,53,54,55)   DOT(56,57,58,59)   DOT(60,61,62,63)
        DOT(64,65,66,67)   DOT(68,69,70,71)   DOT(72,73,74,75)   DOT(76,77,78,79)
        DOT(80,81,82,83)   DOT(84,85,86,87)   DOT(88,89,90,91)   DOT(92,93,94,95)
        DOT(96,97,98,99)   DOT(100,101,102,103) DOT(104,105,106,107) DOT(108,109,110,111)
        DOT(112,113,114,115) DOT(116,117,118,119) DOT(120,121,122,123) DOT(124,125,126,127)
        float accv = ((s0 + s1) + (s2 + s3)) + b1[h];
        result = fmaf(fmaxf(accv, 0.f), W2[h], result);
    }
    out[e] = result;
}

extern "C" void kernel_launch(void* const* d_in, const int* in_sizes, int n_in,
                              void* d_out, int out_size, void* d_ws, size_t ws_size,
                              hipStream_t stream)
{
    const float* x   = (const float*)d_in[0];
    const int*   ei  = (const int*)  d_in[1];
    const float* W1  = (const float*)d_in[2];
    const float* b1  = (const float*)d_in[3];
    const float* W2  = (const float*)d_in[4];
    const float* b2  = (const float*)d_in[5];
    float* out = (float*)d_out;

    int E = out_size;  // 1,000,000
    int block = 256;
    int grid = (E + block - 1) / block;
    edge_bias_kernel<<<grid, block, 0, stream>>>(x, ei, W1, b1, W2, b2, out, E);
}

// Round 4
// 154.912 us; speedup vs baseline: 3.0265x; 2.9820x over previous
//
#include <hip/hip_runtime.h>

// NumericalBiasModule: out[e] = b2 + W2 · relu(W1 · rel(x[src[e]], x[dst[e]]) + b1)
// rel = [ratio | log_ratio | abs_diff | rel_diff], 4*32 = 128 features.
//
// MFMA formulation: per wave-tile = 16 edges.
//   A [16 x 128] = relation features, computed directly in the
//     mfma_f32_16x16x32_bf16 A-fragment layout: lane(l) holds
//     A[m=l&15][k = ks*32 + (l>>4)*8 + j], i.e. lane computes 8 dims
//     (d = (l>>4)*8..+8) of ONE edge (m = l&15) for all 4 feature types.
//   B [128 x 64] = W1^T, held in VGPR fragments loaded ONCE per kernel:
//     lane holds B[k][n] = W1[nt*16 + (l&15)][ks*32 + (l>>4)*8 + j].
//   C [16 x 64]: col = lane&15 (hid), row = (lane>>4)*4 + reg (edge) [m89/m91].
//
// Precision: ratio features reach ~1e8 (x_j ~ 0), so kstep 0 uses a 2-term
// bf16 hi/lo split on BOTH A and B (AhiBhi + AloBhi + AhiBlo); ksteps 1-3
// have |feat| <= ~18.4 and use single bf16. fp32 MFMA accumulate.
// 24 mfma / tile. No LDS. No long-lived per-thread feature array ->
// no scratch spill (rounds 1-3 failure mode).

#define DD    32
#define HID   64
#define RELF  128
#define EPSF  1e-8f

typedef short  bf16x8 __attribute__((ext_vector_type(8)));
typedef float  f32x4  __attribute__((ext_vector_type(4)));

static __device__ __forceinline__ short bf_rne(float f) {        // round-nearest-even bf16
    unsigned u = __builtin_bit_cast(unsigned, f);
    u += 0x7fffu + ((u >> 16) & 1u);
    return (short)(u >> 16);
}
static __device__ __forceinline__ short bf_tr(float f) {         // truncate bf16
    return (short)(__builtin_bit_cast(unsigned, f) >> 16);
}
static __device__ __forceinline__ float bf_f(short h) {          // bf16 -> fp32 (exact)
    unsigned u = ((unsigned)(unsigned short)h) << 16;
    return __builtin_bit_cast(float, u);
}

__global__ __launch_bounds__(256, 2)
void edge_bias_mfma(const float* __restrict__ x,
                    const int*   __restrict__ ei,     // [2, E]
                    const float* __restrict__ W1,     // [64, 128]
                    const float* __restrict__ b1,     // [64]
                    const float* __restrict__ W2,     // [64]
                    const float* __restrict__ b2,     // [1]
                    float* __restrict__ out,          // [E]
                    int E)
{
    const int lane = threadIdx.x & 63;
    const int wave = (blockIdx.x * blockDim.x + threadIdx.x) >> 6;
    const int nwv  = (gridDim.x * blockDim.x) >> 6;
    const int c = lane & 15;      // edge-in-tile for A / hid-col for C
    const int q = lane >> 4;      // k-chunk for A,B / row-quad for C

    // ---- W1 -> B fragments (once per kernel; ~80 VGPRs, live whole kernel) ----
    bf16x8 Bhi[4][4];   // [ntile][kstep]
    bf16x8 Blo[4];      // kstep 0 only (ratio block needs the lo term)
    #pragma unroll
    for (int nt = 0; nt < 4; ++nt) {
        #pragma unroll
        for (int ks = 0; ks < 4; ++ks) {
            const float* wp = W1 + (nt * 16 + c) * RELF + ks * 32 + q * 8;
            float4 w0 = ((const float4*)wp)[0];
            float4 w1 = ((const float4*)wp)[1];
            float wv[8] = {w0.x, w0.y, w0.z, w0.w, w1.x, w1.y, w1.z, w1.w};
            if (ks == 0) {
                #pragma unroll
                for (int j = 0; j < 8; ++j) {
                    short h = bf_tr(wv[j]);
                    Bhi[nt][0][j] = h;
                    Blo[nt][j]    = bf_rne(wv[j] - bf_f(h));
                }
            } else {
                #pragma unroll
                for (int j = 0; j < 8; ++j)
                    Bhi[nt][ks][j] = bf_rne(wv[j]);
            }
        }
    }
    float b1v[4], w2v[4];
    #pragma unroll
    for (int nt = 0; nt < 4; ++nt) {
        b1v[nt] = b1[nt * 16 + c];
        w2v[nt] = W2[nt * 16 + c];
    }
    const float b2s = b2[0];

    const int ntiles = (E + 15) >> 4;
    for (int t = wave; t < ntiles; t += nwv) {
        const int e0 = t << 4;

        // ---- gather x and compute features in A-fragment layout ----
        int em = e0 + c; if (em > E - 1) em = E - 1;   // tail clamp (E%16==0 normally)
        const int src = ei[em];
        const int dst = ei[E + em];
        const float4* pi = (const float4*)(x + (long)src * DD + q * 8);
        const float4* pj = (const float4*)(x + (long)dst * DD + q * 8);
        float4 xi0 = pi[0], xi1 = pi[1];
        float4 xj0 = pj[0], xj1 = pj[1];
        float xiv[8] = {xi0.x, xi0.y, xi0.z, xi0.w, xi1.x, xi1.y, xi1.z, xi1.w};
        float xjv[8] = {xj0.x, xj0.y, xj0.z, xj0.w, xj1.x, xj1.y, xj1.z, xj1.w};

        bf16x8 aRh, aRl, aL, aA, aD;
        #pragma unroll
        for (int j = 0; j < 8; ++j) {
            float xi = xiv[j], xj = xjv[j];
            float ratio = xi * __builtin_amdgcn_rcpf(xj + EPSF);
            float logr  = __logf(xi + EPSF) - __logf(xj + EPSF);
            float ad    = fabsf(xi - xj);
            float rd    = ad * __builtin_amdgcn_rcpf(fmaxf(xi, xj) + EPSF);
            short rh = bf_tr(ratio);
            aRh[j] = rh;
            aRl[j] = bf_rne(ratio - bf_f(rh));
            aL[j]  = bf_rne(logr);
            aA[j]  = bf_rne(ad);
            aD[j]  = bf_rne(rd);
        }

        // ---- layer 1: 24 mfma, acc initialized with b1 ----
        f32x4 acc[4];
        #pragma unroll
        for (int nt = 0; nt < 4; ++nt) {
            acc[nt][0] = b1v[nt]; acc[nt][1] = b1v[nt];
            acc[nt][2] = b1v[nt]; acc[nt][3] = b1v[nt];
        }
        #pragma unroll
        for (int nt = 0; nt < 4; ++nt) {
            acc[nt] = __builtin_amdgcn_mfma_f32_16x16x32_bf16(aRh, Bhi[nt][0], acc[nt], 0, 0, 0);
            acc[nt] = __builtin_amdgcn_mfma_f32_16x16x32_bf16(aRl, Bhi[nt][0], acc[nt], 0, 0, 0);
            acc[nt] = __builtin_amdgcn_mfma_f32_16x16x32_bf16(aRh, Blo[nt],    acc[nt], 0, 0, 0);
            acc[nt] = __builtin_amdgcn_mfma_f32_16x16x32_bf16(aL,  Bhi[nt][1], acc[nt], 0, 0, 0);
            acc[nt] = __builtin_amdgcn_mfma_f32_16x16x32_bf16(aA,  Bhi[nt][2], acc[nt], 0, 0, 0);
            acc[nt] = __builtin_amdgcn_mfma_f32_16x16x32_bf16(aD,  Bhi[nt][3], acc[nt], 0, 0, 0);
        }

        // ---- layer 2: relu, dot with W2 over hid, 16-lane butterfly reduce ----
        // lane holds h[edge = q*4 + r][hid = nt*16 + c] in acc[nt][r]
        float p[4];
        #pragma unroll
        for (int r = 0; r < 4; ++r) {
            float pp = 0.f;
            #pragma unroll
            for (int nt = 0; nt < 4; ++nt)
                pp = fmaf(fmaxf(acc[nt][r], 0.f), w2v[nt], pp);
            pp += __shfl_xor(pp, 1);
            pp += __shfl_xor(pp, 2);
            pp += __shfl_xor(pp, 4);
            pp += __shfl_xor(pp, 8);
            p[r] = pp;
        }
        if (c < 4) {
            const int e = e0 + q * 4 + c;
            if (e < E) {
                float v = (c == 0) ? p[0] : (c == 1) ? p[1] : (c == 2) ? p[2] : p[3];
                out[e] = v + b2s;
            }
        }
    }
}

extern "C" void kernel_launch(void* const* d_in, const int* in_sizes, int n_in,
                              void* d_out, int out_size, void* d_ws, size_t ws_size,
                              hipStream_t stream)
{
    const float* x   = (const float*)d_in[0];
    const int*   ei  = (const int*)  d_in[1];
    const float* W1  = (const float*)d_in[2];
    const float* b1  = (const float*)d_in[3];
    const float* W2  = (const float*)d_in[4];
    const float* b2  = (const float*)d_in[5];
    float* out = (float*)d_out;

    const int E = out_size;  // 1,000,000
    // 1024 blocks x 256 threads = 4096 waves; ~15 tiles/wave amortizes the
    // once-per-kernel W1 fragment setup to ~4%.
    edge_bias_mfma<<<1024, 256, 0, stream>>>(x, ei, W1, b1, W2, b2, out, E);
}

// Round 5
// 151.217 us; speedup vs baseline: 3.1005x; 1.0244x over previous
//
#include <hip/hip_runtime.h>

// NumericalBiasModule: out[e] = b2 + W2 · relu(W1 · rel(x[src], x[dst]) + b1)
// rel = [ratio | log_ratio | abs_diff | rel_diff], 128 features.
//
// MFMA formulation (validated round 4): 16 edges per wave-tile,
// mfma_f32_16x16x32_bf16. lane = (m=lane&15 edge, q=lane>>4 k-chunk);
// A-frag[j] = feat[m][q*8+j]; C/D: col=lane&15, row=q*4+reg.
//
// Round-5 changes (VALU-bound at MfmaUtil=10%, VALUBusy=59%):
//  1. log(x+eps) precomputed PER NODE into ws as bf16 (prep kernel).
//     log_ratio enters the matmul via linearity: (lxi-lxj)·w = lxi·w + lxj·(-w)
//     -> two K-blocks with B = +W and -W (negated once at setup).
//     Gathered bf16x8 IS the A-fragment: zero per-tile log/cvt for this block.
//  2. All per-tile f32->bf16 packs via one v_perm per pair (truncation).
//     Ratio keeps the hi/lo split (dynamic range ~1e8): 3 mfma on that block.
// 28 mfma/tile. No LDS. No long-lived feature array (no scratch spill).

#define DD    32
#define HID   64
#define RELF  128
#define EPSF  1e-8f

typedef short  bf16x8 __attribute__((ext_vector_type(8)));
typedef float  f32x4  __attribute__((ext_vector_type(4)));

union U8 { unsigned u[4]; bf16x8 v; };

// pack hi16(lo-elem) into low short, hi16(hi-elem) into high short (truncate)
static __device__ __forceinline__ unsigned pk_tr(float lo, float hi) {
    return __builtin_amdgcn_perm(__builtin_bit_cast(unsigned, hi),
                                 __builtin_bit_cast(unsigned, lo), 0x07060302u);
}
static __device__ __forceinline__ unsigned rne_bits(float f) {
    unsigned u = __builtin_bit_cast(unsigned, f);
    return u + 0x7fffu + ((u >> 16) & 1u);
}
static __device__ __forceinline__ unsigned pk_rne(float lo, float hi) {
    return __builtin_amdgcn_perm(rne_bits(hi), rne_bits(lo), 0x07060302u);
}
static __device__ __forceinline__ float hi_f32(float f) {   // f truncated to bf16, as f32
    return __builtin_bit_cast(float, __builtin_bit_cast(unsigned, f) & 0xffff0000u);
}

// ---- prep: lx[n*D+d] = bf16_rne(log(x+eps)), 4 elems/thread ----
__global__ __launch_bounds__(256)
void prep_logx(const float* __restrict__ x, unsigned* __restrict__ lx, int nq)
{
    int i = blockIdx.x * blockDim.x + threadIdx.x;
    if (i >= nq) return;
    float4 v = ((const float4*)x)[i];
    uint2 o;
    o.x = pk_rne(__logf(v.x + EPSF), __logf(v.y + EPSF));
    o.y = pk_rne(__logf(v.z + EPSF), __logf(v.w + EPSF));
    ((uint2*)lx)[i] = o;
}

template <int PRE>
__global__ __launch_bounds__(256, 2)
void edge_bias_mfma(const float* __restrict__ x,
                    const int*   __restrict__ ei,     // [2, E]
                    const float* __restrict__ W1,     // [64, 128]
                    const float* __restrict__ b1,
                    const float* __restrict__ W2,
                    const float* __restrict__ b2,
                    const short* __restrict__ lx,     // [N, 32] bf16 log(x+eps)
                    float* __restrict__ out,
                    int E)
{
    const int lane = threadIdx.x & 63;
    const int wave = (blockIdx.x * blockDim.x + threadIdx.x) >> 6;
    const int nwv  = (gridDim.x * blockDim.x) >> 6;
    const int c = lane & 15;      // edge-in-tile (A) / hid-col (C)
    const int q = lane >> 4;      // k-chunk (A,B) / row-quad (C)

    // ---- B fragments, once per kernel ----
    // blocks: W0 = W1 cols 0..31 (ratio, hi+lo split), WL = cols 32..63 (logs,
    // +/-), WA = cols 64..95 (abs), WD = cols 96..127 (rel_diff)
    bf16x8 W0h[4], W0l[4], WL[4], WLn[4], WA[4], WDm[4];
    #pragma unroll
    for (int nt = 0; nt < 4; ++nt) {
        const float* wr = W1 + (nt * 16 + c) * RELF + q * 8;
        U8 h, l, t;
        #pragma unroll
        for (int p = 0; p < 4; ++p) {
            float w0 = wr[2 * p], w1 = wr[2 * p + 1];
            h.u[p] = pk_tr(w0, w1);
            l.u[p] = pk_rne(w0 - hi_f32(w0), w1 - hi_f32(w1));
        }
        W0h[nt] = h.v; W0l[nt] = l.v;
        #pragma unroll
        for (int p = 0; p < 4; ++p)
            t.u[p] = pk_rne(wr[32 + 2 * p], wr[32 + 2 * p + 1]);
        WL[nt] = t.v;
        #pragma unroll
        for (int p = 0; p < 4; ++p) t.u[p] ^= 0x80008000u;   // negate bf16 pair
        WLn[nt] = t.v;
        #pragma unroll
        for (int p = 0; p < 4; ++p)
            t.u[p] = pk_rne(wr[64 + 2 * p], wr[64 + 2 * p + 1]);
        WA[nt] = t.v;
        #pragma unroll
        for (int p = 0; p < 4; ++p)
            t.u[p] = pk_rne(wr[96 + 2 * p], wr[96 + 2 * p + 1]);
        WDm[nt] = t.v;
    }
    float b1v[4], w2v[4];
    #pragma unroll
    for (int nt = 0; nt < 4; ++nt) {
        b1v[nt] = b1[nt * 16 + c];
        w2v[nt] = W2[nt * 16 + c];
    }
    const float b2s = b2[0];

    const int ntiles = (E + 15) >> 4;
    for (int t = wave; t < ntiles; t += nwv) {
        const int e0 = t << 4;
        int em = e0 + c; if (em > E - 1) em = E - 1;
        const int src = ei[em];
        const int dst = ei[E + em];

        const float* pxi = x + (long)src * DD + q * 8;
        const float* pxj = x + (long)dst * DD + q * 8;
        float4 xi0 = ((const float4*)pxi)[0], xi1 = ((const float4*)pxi)[1];
        float4 xj0 = ((const float4*)pxj)[0], xj1 = ((const float4*)pxj)[1];
        float xiv[8] = {xi0.x, xi0.y, xi0.z, xi0.w, xi1.x, xi1.y, xi1.z, xi1.w};
        float xjv[8] = {xj0.x, xj0.y, xj0.z, xj0.w, xj1.x, xj1.y, xj1.z, xj1.w};

        bf16x8 aLi, aLj;
        if constexpr (PRE) {
            aLi = *(const bf16x8*)(lx + (long)src * DD + q * 8);
            aLj = *(const bf16x8*)(lx + (long)dst * DD + q * 8);
        } else {
            U8 ti, tj;
            #pragma unroll
            for (int p = 0; p < 4; ++p) {
                ti.u[p] = pk_rne(__logf(xiv[2*p] + EPSF), __logf(xiv[2*p+1] + EPSF));
                tj.u[p] = pk_rne(__logf(xjv[2*p] + EPSF), __logf(xjv[2*p+1] + EPSF));
            }
            aLi = ti.v; aLj = tj.v;
        }

        // ---- features -> packed A-fragments ----
        U8 R, Rl, Aa, Dd;
        #pragma unroll
        for (int p = 0; p < 4; ++p) {
            float a0 = xiv[2*p], a1 = xiv[2*p+1];
            float c0 = xjv[2*p], c1 = xjv[2*p+1];
            float r0 = a0 * __builtin_amdgcn_rcpf(c0 + EPSF);
            float r1 = a1 * __builtin_amdgcn_rcpf(c1 + EPSF);
            float d0 = fabsf(a0 - c0), d1 = fabsf(a1 - c1);
            float g0 = d0 * __builtin_amdgcn_rcpf(fmaxf(a0, c0) + EPSF);
            float g1 = d1 * __builtin_amdgcn_rcpf(fmaxf(a1, c1) + EPSF);
            R.u[p]  = pk_tr(r0, r1);
            Rl.u[p] = pk_tr(r0 - hi_f32(r0), r1 - hi_f32(r1));
            Aa.u[p] = pk_tr(d0, d1);
            Dd.u[p] = pk_tr(g0, g1);
        }

        // ---- layer 1: 28 mfma ----
        f32x4 acc[4];
        #pragma unroll
        for (int nt = 0; nt < 4; ++nt) {
            acc[nt][0] = b1v[nt]; acc[nt][1] = b1v[nt];
            acc[nt][2] = b1v[nt]; acc[nt][3] = b1v[nt];
        }
        #pragma unroll
        for (int nt = 0; nt < 4; ++nt) {
            acc[nt] = __builtin_amdgcn_mfma_f32_16x16x32_bf16(R.v,  W0h[nt], acc[nt], 0, 0, 0);
            acc[nt] = __builtin_amdgcn_mfma_f32_16x16x32_bf16(Rl.v, W0h[nt], acc[nt], 0, 0, 0);
            acc[nt] = __builtin_amdgcn_mfma_f32_16x16x32_bf16(R.v,  W0l[nt], acc[nt], 0, 0, 0);
            acc[nt] = __builtin_amdgcn_mfma_f32_16x16x32_bf16(aLi,  WL[nt],  acc[nt], 0, 0, 0);
            acc[nt] = __builtin_amdgcn_mfma_f32_16x16x32_bf16(aLj,  WLn[nt], acc[nt], 0, 0, 0);
            acc[nt] = __builtin_amdgcn_mfma_f32_16x16x32_bf16(Aa.v, WA[nt],  acc[nt], 0, 0, 0);
            acc[nt] = __builtin_amdgcn_mfma_f32_16x16x32_bf16(Dd.v, WDm[nt], acc[nt], 0, 0, 0);
        }

        // ---- layer 2 + reduce: lane holds h[edge=q*4+r][hid=nt*16+c] ----
        float p[4];
        #pragma unroll
        for (int r = 0; r < 4; ++r) {
            float pp = 0.f;
            #pragma unroll
            for (int nt = 0; nt < 4; ++nt)
                pp = fmaf(fmaxf(acc[nt][r], 0.f), w2v[nt], pp);
            pp += __shfl_xor(pp, 1);
            pp += __shfl_xor(pp, 2);
            pp += __shfl_xor(pp, 4);
            pp += __shfl_xor(pp, 8);
            p[r] = pp;
        }
        if (c < 4) {
            const int e = e0 + q * 4 + c;
            if (e < E) {
                float v = (c == 0) ? p[0] : (c == 1) ? p[1] : (c == 2) ? p[2] : p[3];
                out[e] = v + b2s;
            }
        }
    }
}

extern "C" void kernel_launch(void* const* d_in, const int* in_sizes, int n_in,
                              void* d_out, int out_size, void* d_ws, size_t ws_size,
                              hipStream_t stream)
{
    const float* x   = (const float*)d_in[0];
    const int*   ei  = (const int*)  d_in[1];
    const float* W1  = (const float*)d_in[2];
    const float* b1  = (const float*)d_in[3];
    const float* W2  = (const float*)d_in[4];
    const float* b2  = (const float*)d_in[5];
    float* out = (float*)d_out;

    const int E  = out_size;       // 1,000,000
    const int Nd = in_sizes[0];    // N*D = 3,200,000
    short* lx = (short*)d_ws;

    const bool pre = ws_size >= (size_t)Nd * sizeof(short) && (Nd % 4) == 0;
    if (pre) {
        const int nq = Nd / 4;
        prep_logx<<<(nq + 255) / 256, 256, 0, stream>>>(x, (unsigned*)lx, nq);
        edge_bias_mfma<1><<<1024, 256, 0, stream>>>(x, ei, W1, b1, W2, b2, lx, out, E);
    } else {
        edge_bias_mfma<0><<<1024, 256, 0, stream>>>(x, ei, W1, b1, W2, b2, lx, out, E);
    }
}

// Round 6
// 144.886 us; speedup vs baseline: 3.2360x; 1.0437x over previous
//
#include <hip/hip_runtime.h>

// NumericalBiasModule: out[e] = b2 + W2 · relu(W1 · rel(x[src], x[dst]) + b1)
// rel = [ratio | log_ratio | abs_diff | rel_diff], 128 features.
//
// MFMA formulation (validated r4/r5): 16 edges per wave-tile,
// mfma_f32_16x16x32_bf16. lane = (m=lane&15 edge, q=lane>>4 k-chunk);
// A-frag[j] = feat[m][q*8+j]; C/D: col=lane&15, row=q*4+reg.
// log(x+eps) precomputed per node (bf16) -> log_ratio via +/-W K-blocks.
// Ratio block keeps bf16 hi/lo split on A and W (dyn range ~1e7).
//
// Round-6 change (latency-serialized: 13k cyc/tile vs ~500 cyc compute):
// software pipeline -- idx prefetched 2 tiles ahead, x/lx gathers issued
// 1 tile ahead, so each tile's ~500-900 cyc gather latency overlaps the
// previous tile's compute. Math unchanged.

#define DD    32
#define HID   64
#define RELF  128
#define EPSF  1e-8f

typedef short  bf16x8 __attribute__((ext_vector_type(8)));
typedef float  f32x4  __attribute__((ext_vector_type(4)));

union U8 { unsigned u[4]; bf16x8 v; };

static __device__ __forceinline__ unsigned pk_tr(float lo, float hi) {
    return __builtin_amdgcn_perm(__builtin_bit_cast(unsigned, hi),
                                 __builtin_bit_cast(unsigned, lo), 0x07060302u);
}
static __device__ __forceinline__ unsigned rne_bits(float f) {
    unsigned u = __builtin_bit_cast(unsigned, f);
    return u + 0x7fffu + ((u >> 16) & 1u);
}
static __device__ __forceinline__ unsigned pk_rne(float lo, float hi) {
    return __builtin_amdgcn_perm(rne_bits(hi), rne_bits(lo), 0x07060302u);
}
static __device__ __forceinline__ float hi_f32(float f) {
    return __builtin_bit_cast(float, __builtin_bit_cast(unsigned, f) & 0xffff0000u);
}

__global__ __launch_bounds__(256)
void prep_logx(const float* __restrict__ x, unsigned* __restrict__ lx, int nq)
{
    int i = blockIdx.x * blockDim.x + threadIdx.x;
    if (i >= nq) return;
    float4 v = ((const float4*)x)[i];
    uint2 o;
    o.x = pk_rne(__logf(v.x + EPSF), __logf(v.y + EPSF));
    o.y = pk_rne(__logf(v.z + EPSF), __logf(v.w + EPSF));
    ((uint2*)lx)[i] = o;
}

template <int PRE>
__global__ __launch_bounds__(256, 2)
void edge_bias_mfma(const float* __restrict__ x,
                    const int*   __restrict__ ei,     // [2, E]
                    const float* __restrict__ W1,     // [64, 128]
                    const float* __restrict__ b1,
                    const float* __restrict__ W2,
                    const float* __restrict__ b2,
                    const short* __restrict__ lx,     // [N, 32] bf16 log(x+eps)
                    float* __restrict__ out,
                    int E)
{
    const int lane = threadIdx.x & 63;
    const int wave = (blockIdx.x * blockDim.x + threadIdx.x) >> 6;
    const int nwv  = (gridDim.x * blockDim.x) >> 6;
    const int c = lane & 15;      // edge-in-tile (A) / hid-col (C)
    const int q = lane >> 4;      // k-chunk (A,B) / row-quad (C)

    // ---- B fragments, once per kernel ----
    bf16x8 W0h[4], W0l[4], WL[4], WLn[4], WA[4], WDm[4];
    #pragma unroll
    for (int nt = 0; nt < 4; ++nt) {
        const float* wr = W1 + (nt * 16 + c) * RELF + q * 8;
        U8 h, l, tt;
        #pragma unroll
        for (int p = 0; p < 4; ++p) {
            float w0 = wr[2 * p], w1 = wr[2 * p + 1];
            h.u[p] = pk_tr(w0, w1);
            l.u[p] = pk_rne(w0 - hi_f32(w0), w1 - hi_f32(w1));
        }
        W0h[nt] = h.v; W0l[nt] = l.v;
        #pragma unroll
        for (int p = 0; p < 4; ++p)
            tt.u[p] = pk_rne(wr[32 + 2 * p], wr[32 + 2 * p + 1]);
        WL[nt] = tt.v;
        #pragma unroll
        for (int p = 0; p < 4; ++p) tt.u[p] ^= 0x80008000u;
        WLn[nt] = tt.v;
        #pragma unroll
        for (int p = 0; p < 4; ++p)
            tt.u[p] = pk_rne(wr[64 + 2 * p], wr[64 + 2 * p + 1]);
        WA[nt] = tt.v;
        #pragma unroll
        for (int p = 0; p < 4; ++p)
            tt.u[p] = pk_rne(wr[96 + 2 * p], wr[96 + 2 * p + 1]);
        WDm[nt] = tt.v;
    }
    float b1v[4], w2v[4];
    #pragma unroll
    for (int nt = 0; nt < 4; ++nt) {
        b1v[nt] = b1[nt * 16 + c];
        w2v[nt] = W2[nt * 16 + c];
    }
    const float b2s = b2[0];

    const int ntiles = (E + 15) >> 4;
    int t = wave;
    if (t >= ntiles) return;

    // ---- pipeline state ----
    // data(t): gathers issued; idx(t+nwv): resident
    float4 xi0C, xi1C, xj0C, xj1C;
    bf16x8 LiC, LjC;
    int srcN, dstN;

    {   // prologue: gathers for tile t
        int em = (t << 4) + c; if (em > E - 1) em = E - 1;
        int s = ei[em], d = ei[E + em];
        const float* pi = x + (long)s * DD + q * 8;
        const float* pj = x + (long)d * DD + q * 8;
        xi0C = ((const float4*)pi)[0]; xi1C = ((const float4*)pi)[1];
        xj0C = ((const float4*)pj)[0]; xj1C = ((const float4*)pj)[1];
        if (PRE) {
            LiC = *(const bf16x8*)(lx + (long)s * DD + q * 8);
            LjC = *(const bf16x8*)(lx + (long)d * DD + q * 8);
        }
    }
    {   // prologue: idx for tile t+nwv (clamped if past end)
        int t1 = t + nwv; if (t1 >= ntiles) t1 = t;
        int em = (t1 << 4) + c; if (em > E - 1) em = E - 1;
        srcN = ei[em]; dstN = ei[E + em];
    }

    for (; t < ntiles; t += nwv) {
        // 1. issue gathers for t+nwv (idx already resident)
        float4 xi0N, xi1N, xj0N, xj1N;
        bf16x8 LiN, LjN;
        {
            const float* pi = x + (long)srcN * DD + q * 8;
            const float* pj = x + (long)dstN * DD + q * 8;
            xi0N = ((const float4*)pi)[0]; xi1N = ((const float4*)pi)[1];
            xj0N = ((const float4*)pj)[0]; xj1N = ((const float4*)pj)[1];
            if (PRE) {
                LiN = *(const bf16x8*)(lx + (long)srcN * DD + q * 8);
                LjN = *(const bf16x8*)(lx + (long)dstN * DD + q * 8);
            }
        }
        // 2. load idx for t+2*nwv
        int srcN2, dstN2;
        {
            int t2 = t + 2 * nwv; if (t2 >= ntiles) t2 = t;
            int em = (t2 << 4) + c; if (em > E - 1) em = E - 1;
            srcN2 = ei[em]; dstN2 = ei[E + em];
        }

        // 3. compute tile t (data(t) waits resolve here, overlapped by
        //    the previous iteration's compute)
        const int e0 = t << 4;
        float xiv[8] = {xi0C.x, xi0C.y, xi0C.z, xi0C.w, xi1C.x, xi1C.y, xi1C.z, xi1C.w};
        float xjv[8] = {xj0C.x, xj0C.y, xj0C.z, xj0C.w, xj1C.x, xj1C.y, xj1C.z, xj1C.w};

        bf16x8 aLi, aLj;
        if constexpr (PRE) {
            aLi = LiC; aLj = LjC;
        } else {
            U8 ti, tj;
            #pragma unroll
            for (int p = 0; p < 4; ++p) {
                ti.u[p] = pk_rne(__logf(xiv[2*p] + EPSF), __logf(xiv[2*p+1] + EPSF));
                tj.u[p] = pk_rne(__logf(xjv[2*p] + EPSF), __logf(xjv[2*p+1] + EPSF));
            }
            aLi = ti.v; aLj = tj.v;
        }

        U8 R, Rl, Aa, Dd;
        #pragma unroll
        for (int p = 0; p < 4; ++p) {
            float a0 = xiv[2*p], a1 = xiv[2*p+1];
            float c0 = xjv[2*p], c1 = xjv[2*p+1];
            float r0 = a0 * __builtin_amdgcn_rcpf(c0 + EPSF);
            float r1 = a1 * __builtin_amdgcn_rcpf(c1 + EPSF);
            float d0 = fabsf(a0 - c0), d1 = fabsf(a1 - c1);
            float g0 = d0 * __builtin_amdgcn_rcpf(fmaxf(a0, c0) + EPSF);
            float g1 = d1 * __builtin_amdgcn_rcpf(fmaxf(a1, c1) + EPSF);
            R.u[p]  = pk_tr(r0, r1);
            Rl.u[p] = pk_tr(r0 - hi_f32(r0), r1 - hi_f32(r1));
            Aa.u[p] = pk_tr(d0, d1);
            Dd.u[p] = pk_tr(g0, g1);
        }

        f32x4 acc[4];
        #pragma unroll
        for (int nt = 0; nt < 4; ++nt) {
            acc[nt][0] = b1v[nt]; acc[nt][1] = b1v[nt];
            acc[nt][2] = b1v[nt]; acc[nt][3] = b1v[nt];
        }
        #pragma unroll
        for (int nt = 0; nt < 4; ++nt) {
            acc[nt] = __builtin_amdgcn_mfma_f32_16x16x32_bf16(R.v,  W0h[nt], acc[nt], 0, 0, 0);
            acc[nt] = __builtin_amdgcn_mfma_f32_16x16x32_bf16(Rl.v, W0h[nt], acc[nt], 0, 0, 0);
            acc[nt] = __builtin_amdgcn_mfma_f32_16x16x32_bf16(R.v,  W0l[nt], acc[nt], 0, 0, 0);
            acc[nt] = __builtin_amdgcn_mfma_f32_16x16x32_bf16(aLi,  WL[nt],  acc[nt], 0, 0, 0);
            acc[nt] = __builtin_amdgcn_mfma_f32_16x16x32_bf16(aLj,  WLn[nt], acc[nt], 0, 0, 0);
            acc[nt] = __builtin_amdgcn_mfma_f32_16x16x32_bf16(Aa.v, WA[nt],  acc[nt], 0, 0, 0);
            acc[nt] = __builtin_amdgcn_mfma_f32_16x16x32_bf16(Dd.v, WDm[nt], acc[nt], 0, 0, 0);
        }

        float p[4];
        #pragma unroll
        for (int r = 0; r < 4; ++r) {
            float pp = 0.f;
            #pragma unroll
            for (int nt = 0; nt < 4; ++nt)
                pp = fmaf(fmaxf(acc[nt][r], 0.f), w2v[nt], pp);
            pp += __shfl_xor(pp, 1);
            pp += __shfl_xor(pp, 2);
            pp += __shfl_xor(pp, 4);
            pp += __shfl_xor(pp, 8);
            p[r] = pp;
        }
        if (c < 4) {
            const int e = e0 + q * 4 + c;
            if (e < E) {
                float v = (c == 0) ? p[0] : (c == 1) ? p[1] : (c == 2) ? p[2] : p[3];
                out[e] = v + b2s;
            }
        }

        // 4. rotate pipeline
        xi0C = xi0N; xi1C = xi1N; xj0C = xj0N; xj1C = xj1N;
        LiC = LiN;  LjC = LjN;
        srcN = srcN2; dstN = dstN2;
    }
}

extern "C" void kernel_launch(void* const* d_in, const int* in_sizes, int n_in,
                              void* d_out, int out_size, void* d_ws, size_t ws_size,
                              hipStream_t stream)
{
    const float* x   = (const float*)d_in[0];
    const int*   ei  = (const int*)  d_in[1];
    const float* W1  = (const float*)d_in[2];
    const float* b1  = (const float*)d_in[3];
    const float* W2  = (const float*)d_in[4];
    const float* b2  = (const float*)d_in[5];
    float* out = (float*)d_out;

    const int E  = out_size;       // 1,000,000
    const int Nd = in_sizes[0];    // N*D = 3,200,000
    short* lx = (short*)d_ws;

    const bool pre = ws_size >= (size_t)Nd * sizeof(short) && (Nd % 4) == 0;
    if (pre) {
        const int nq = Nd / 4;
        prep_logx<<<(nq + 255) / 256, 256, 0, stream>>>(x, (unsigned*)lx, nq);
        edge_bias_mfma<1><<<1024, 256, 0, stream>>>(x, ei, W1, b1, W2, b2, lx, out, E);
    } else {
        edge_bias_mfma<0><<<1024, 256, 0, stream>>>(x, ei, W1, b1, W2, b2, lx, out, E);
    }
}